// Round 3
// baseline (1922.036 us; speedup 1.0000x reference)
//
#include <hip/hip_runtime.h>
#include <stdint.h>

#define INCH 512
#define HIDW 512
#define CATW 2560
#define OUTW 256
#define BN_EPS 1e-5f

typedef __bf16 bf16x8 __attribute__((ext_vector_type(8)));
typedef float f32x4 __attribute__((ext_vector_type(4)));

__device__ __forceinline__ unsigned short f2bf(float f) {
  union { float f; unsigned u; } v; v.f = f;
  unsigned r = v.u + 0x7FFFu + ((v.u >> 16) & 1u);   // RNE
  return (unsigned short)(r >> 16);
}

__device__ __forceinline__ void pack4(unsigned short* dst, float a, float b, float c, float d) {
  unsigned lo = (unsigned)f2bf(a) | ((unsigned)f2bf(b) << 16);
  unsigned hi = (unsigned)f2bf(c) | ((unsigned)f2bf(d) << 16);
  *reinterpret_cast<uint2*>(dst) = make_uint2(lo, hi);
}

// ---------------- conversion / packing kernels ----------------

__global__ void cvt_bf16_kernel(const float* __restrict__ in, unsigned short* __restrict__ out, int n4) {
  int g = blockIdx.x * blockDim.x + threadIdx.x;
  if (g >= n4) return;
  int base = g * 4;
  float4 v = *reinterpret_cast<const float4*>(in + base);
  pack4(out + base, v.x, v.y, v.z, v.w);
}

// w1[z*512+j][kk] = kk<512 ? Wl5[z][j][kk] : Wr5[z][j][kk-512]   (2560 x 1024)
__global__ void pack_w1_kernel(const float* __restrict__ Wl, const float* __restrict__ Wr,
                               unsigned short* __restrict__ out) {
  int g = blockIdx.x * blockDim.x + threadIdx.x;
  int base = g * 4;
  if (base >= 5 * 512 * 1024) return;
  int zj = base >> 10;
  int kk = base & 1023;
  const float* src = (kk < 512) ? (Wl + (size_t)zj * 512 + kk)
                                : (Wr + (size_t)zj * 512 + (kk - 512));
  float4 v = *reinterpret_cast<const float4*>(src);
  pack4(out + base, v.x, v.y, v.z, v.w);
}

// W[j2][c] = j2<256 ? Wa[j2][c] : Wb[j2-256][c]   (512 x 2560)
__global__ void pack_lr_kernel(const float* __restrict__ Wa, const float* __restrict__ Wb,
                               unsigned short* __restrict__ out) {
  int g = blockIdx.x * blockDim.x + threadIdx.x;
  int base = g * 4;
  if (base >= 512 * CATW) return;
  int j2 = base / CATW;
  int c = base % CATW;
  const float* src = (j2 < OUTW) ? (Wa + (size_t)j2 * CATW + c)
                                 : (Wb + (size_t)(j2 - OUTW) * CATW + c);
  float4 v = *reinterpret_cast<const float4*>(src);
  pack4(out + base, v.x, v.y, v.z, v.w);
}

// meanb[i][c] = bf16(agg[i][c] / max(cnt[i],1))   ([N,512] per relation)
__global__ void mean_cvt_kernel(const float* __restrict__ agg, const float* __restrict__ cnt,
                                unsigned short* __restrict__ out, int n4) {
  int g = blockIdx.x * blockDim.x + threadIdx.x;
  if (g >= n4) return;
  int base = g * 4;
  int i = base >> 9;
  float inv = 1.0f / fmaxf(cnt[i], 1.0f);
  float4 v = *reinterpret_cast<const float4*>(agg + base);
  pack4(out + base, v.x * inv, v.y * inv, v.z * inv, v.w * inv);
}

// ---------------- edge scatter kernels ----------------

// one block per edge; only edges of relation `rel` do work
__global__ void scatter1_kernel(const float* __restrict__ x, const int* __restrict__ ei,
                                const int* __restrict__ ea, float* __restrict__ agg,
                                float* __restrict__ cnt, int E, int rel) {
  int e = blockIdx.x;
  if (ea[e] != rel) return;
  int s = ei[e];
  int d = ei[E + e];
  const float4* xs = reinterpret_cast<const float4*>(x + (size_t)s * INCH);
  float* dp = agg + (size_t)d * 512;
  float4 v = xs[threadIdx.x];
  int f = threadIdx.x * 4;
  atomicAdd(dp + f + 0, v.x);
  atomicAdd(dp + f + 1, v.y);
  atomicAdd(dp + f + 2, v.z);
  atomicAdd(dp + f + 3, v.w);
  if (threadIdx.x == 0) atomicAdd(cnt + d, 1.0f);
}

__global__ void scatter2_kernel(const float* __restrict__ z, const int* __restrict__ ei,
                                float* __restrict__ agg2, float* __restrict__ deg, int E) {
  int e = blockIdx.x;
  int s = ei[e];
  int d = ei[E + e];
  const float4* zs = reinterpret_cast<const float4*>(z + (size_t)s * 512);
  float* dp = agg2 + (size_t)d * 512;
  float4 v = zs[threadIdx.x];
  int f = threadIdx.x * 4;
  atomicAdd(dp + f + 0, v.x);
  atomicAdd(dp + f + 1, v.y);
  atomicAdd(dp + f + 2, v.z);
  atomicAdd(dp + f + 3, v.w);
  if (threadIdx.x == 0) atomicAdd(deg + d, 1.0f);
}

// ---------------- MFMA GEMM ----------------
// C[i][j] = sum_k A[i][k] * B[j][k]   (B row-major, K contiguous)
// MODE 0: A = [meanb_k | xb] (both [N,512], K=1024), B = w1+k*512*1024,
//         epilogue bias -> ReLU -> BN -> hb[i][zoff+j] (bf16)
// MODE 1: A = hb (K=2560), B = w2, epilogue raw f32 -> zbuf [N,512]
// MODE 2: A = hb (K=2560), B = w3, epilogue + agg2/deg + bias -> d_out
template<int MODE>
__global__ __launch_bounds__(256, 2)
void gemm_kernel(const unsigned short* __restrict__ A,
                 const unsigned short* __restrict__ A2,
                 const unsigned short* __restrict__ B,
                 unsigned short* __restrict__ hOut,
                 float* __restrict__ fOut,
                 const float* __restrict__ p0,   // MODE0: bl5   MODE2: agg2
                 const float* __restrict__ p1,   // MODE0: rmean MODE2: deg
                 const float* __restrict__ p2,   // MODE0: rvar  MODE2: bmu
                 const float* __restrict__ p3,   // MODE0: gamma MODE2: blv
                 const float* __restrict__ p4,   // MODE0: beta
                 int zoff, int M)
{
  constexpr int KTOT = (MODE == 0) ? (2 * INCH) : CATW;
  constexpr int KT = KTOT / 32;

  const int rowBase = blockIdx.x * 128;
  const int nBase = blockIdx.y * 128;

  __shared__ uint4 As[512];
  __shared__ uint4 Bs[512];

  const int tid = threadIdx.x;
  const int lane = tid & 63;
  const int wave = tid >> 6;
  const int wr = wave >> 1, wc = wave & 1;
  const int lr = lane & 15, kg = lane >> 4;

  // staging: thread t handles (kgroup, row) chunks of 16B
  const int skg = tid & 3;
  const int sr = tid >> 2;                              // 0..63
  const int pA0 = skg * 128 + (sr ^ (skg << 1));        // XOR swizzle
  const int pA1 = skg * 128 + ((sr + 64) ^ (skg << 1));

  int ga0 = rowBase + sr;      if (ga0 >= M) ga0 = M - 1;
  int ga1 = rowBase + sr + 64; if (ga1 >= M) ga1 = M - 1;
  const size_t gb0 = (size_t)(nBase + sr) * KTOT;
  const size_t gb1 = (size_t)(nBase + sr + 64) * KTOT;

  int aslot[4], bslot[4];
#pragma unroll
  for (int m = 0; m < 4; ++m) {
    int r = wr * 64 + m * 16 + lr;
    aslot[m] = kg * 128 + (r ^ (kg << 1));
    int c = wc * 64 + m * 16 + lr;
    bslot[m] = kg * 128 + (c ^ (kg << 1));
  }

  f32x4 acc[4][4] = {};

  auto loadA = [&](int kt, int grow) -> uint4 {
    const int kk = kt * 32 + skg * 8;
    const unsigned short* s;
    if (MODE == 0) {
      if (kk < INCH) s = A + (size_t)grow * INCH + kk;
      else           s = A2 + (size_t)grow * INCH + (kk - INCH);
    } else {
      s = A + (size_t)grow * CATW + kk;
    }
    return *reinterpret_cast<const uint4*>(s);
  };
  auto loadB = [&](int kt, size_t gb) -> uint4 {
    const int kk = kt * 32 + skg * 8;
    return *reinterpret_cast<const uint4*>(B + gb + kk);
  };

  uint4 ra0 = loadA(0, ga0), ra1 = loadA(0, ga1);
  uint4 rb0 = loadB(0, gb0), rb1 = loadB(0, gb1);

  for (int kt = 0; kt < KT; ++kt) {
    __syncthreads();
    As[pA0] = ra0; As[pA1] = ra1;
    Bs[pA0] = rb0; Bs[pA1] = rb1;
    __syncthreads();
    if (kt + 1 < KT) {
      ra0 = loadA(kt + 1, ga0); ra1 = loadA(kt + 1, ga1);
      rb0 = loadB(kt + 1, gb0); rb1 = loadB(kt + 1, gb1);
    }
    bf16x8 af[4], bfv[4];
#pragma unroll
    for (int m = 0; m < 4; ++m) af[m] = *reinterpret_cast<const bf16x8*>(&As[aslot[m]]);
#pragma unroll
    for (int n = 0; n < 4; ++n) bfv[n] = *reinterpret_cast<const bf16x8*>(&Bs[bslot[n]]);
#pragma unroll
    for (int m = 0; m < 4; ++m)
#pragma unroll
      for (int n = 0; n < 4; ++n)
        acc[m][n] = __builtin_amdgcn_mfma_f32_16x16x32_bf16(af[m], bfv[n], acc[m][n], 0, 0, 0);
  }

#pragma unroll
  for (int n = 0; n < 4; ++n) {
    const int j = nBase + wc * 64 + n * 16 + lr;
    if (MODE == 0) {
      const int ch = zoff + j;
      const float bias = p0[ch];
      const float scale = rsqrtf(p2[ch] + BN_EPS) * p3[ch];
      const float rm = p1[ch], be = p4[ch];
#pragma unroll
      for (int m = 0; m < 4; ++m) {
        const int ib = rowBase + wr * 64 + m * 16 + kg * 4;
#pragma unroll
        for (int rr = 0; rr < 4; ++rr) {
          const int i = ib + rr;
          if (i < M) {
            float v = acc[m][n][rr] + bias;   // SAGE output
            v = fmaxf(v, 0.0f);               // ReLU FIRST (reference order)
            v = (v - rm) * scale + be;        // BN SECOND
            hOut[(size_t)i * CATW + ch] = f2bf(v);
          }
        }
      }
    } else if (MODE == 1) {
#pragma unroll
      for (int m = 0; m < 4; ++m) {
        const int ib = rowBase + wr * 64 + m * 16 + kg * 4;
#pragma unroll
        for (int rr = 0; rr < 4; ++rr) {
          const int i = ib + rr;
          if (i < M) fOut[(size_t)i * 512 + j] = acc[m][n][rr];
        }
      }
    } else {
      const float bias = (j < OUTW) ? p2[j] : p3[j - OUTW];
#pragma unroll
      for (int m = 0; m < 4; ++m) {
        const int ib = rowBase + wr * 64 + m * 16 + kg * 4;
#pragma unroll
        for (int rr = 0; rr < 4; ++rr) {
          const int i = ib + rr;
          if (i < M) {
            const float dg = fmaxf(p1[i], 1.0f);
            const float v = acc[m][n][rr] + p0[(size_t)i * 512 + j] / dg + bias;
            size_t o = (j < OUTW) ? ((size_t)i * OUTW + j)
                                  : ((size_t)M * OUTW + (size_t)i * OUTW + (j - OUTW));
            fOut[o] = v;
          }
        }
      }
    }
  }
}

// ---------------- launch ----------------

extern "C" void kernel_launch(void* const* d_in, const int* in_sizes, int n_in,
                              void* d_out, int out_size, void* d_ws, size_t ws_size,
                              hipStream_t stream) {
  const float* x     = (const float*)d_in[0];
  const int*   ei    = (const int*)d_in[1];
  const int*   ea    = (const int*)d_in[2];
  const float* Wl5   = (const float*)d_in[3];
  const float* Wr5   = (const float*)d_in[4];
  const float* bl5   = (const float*)d_in[5];
  const float* Wmu_l = (const float*)d_in[6];
  const float* Wmu_r = (const float*)d_in[7];
  const float* bmu   = (const float*)d_in[8];
  const float* Wlv_l = (const float*)d_in[9];
  const float* Wlv_r = (const float*)d_in[10];
  const float* blv   = (const float*)d_in[11];
  const float* gamma = (const float*)d_in[12];
  const float* beta  = (const float*)d_in[13];
  const float* rmean = (const float*)d_in[14];
  const float* rvar  = (const float*)d_in[15];
  (void)n_in; (void)out_size;

  const int N = in_sizes[0] / INCH;   // 20000
  const int E = in_sizes[2];          // 100000

  // ---- workspace layout (~186 MB total) ----
  char* ws = (char*)d_ws;
  size_t off = 0;
  auto take = [&](size_t bytes) { char* p = ws + off; off += (bytes + 255) & ~(size_t)255; return p; };
  unsigned short* hb   = (unsigned short*)take((size_t)N * CATW * 2);  // 102.4 MB, layer-1 out
  float* R1f = (float*)take((size_t)N * 512 * 4);                      // 41 MB: agg_k, later agg2
  char*  R2  = take((size_t)N * 512 * 4);                              // 41 MB: meanb|xb, later zbuf
  float* cntk = (float*)take((size_t)N * 4);
  float* deg  = (float*)take((size_t)N * 4);
  unsigned short* w1 = (unsigned short*)take((size_t)5 * 512 * 1024 * 2);
  unsigned short* w2 = (unsigned short*)take((size_t)512 * CATW * 2);
  unsigned short* w3 = (unsigned short*)take((size_t)512 * CATW * 2);
  if (off > ws_size) return;  // diagnostic guard: clean absmax-fail instead of page-fault abort

  unsigned short* meanb = (unsigned short*)R2;                 // [N,512] bf16
  unsigned short* xb    = (unsigned short*)(R2 + (size_t)N * 512 * 2);
  float* zbuf = (float*)R2;                                    // [N,512] f32 (after layer-1)
  float* agg2 = R1f;                                           // [N,512] f32 (after layer-1)

  cvt_bf16_kernel<<<dim3((N * INCH / 4 + 255) / 256), 256, 0, stream>>>(x, xb, N * INCH / 4);
  pack_w1_kernel<<<dim3((5 * 512 * 1024 / 4 + 255) / 256), 256, 0, stream>>>(Wl5, Wr5, w1);
  pack_lr_kernel<<<dim3((512 * CATW / 4 + 255) / 256), 256, 0, stream>>>(Wmu_l, Wlv_l, w2);
  pack_lr_kernel<<<dim3((512 * CATW / 4 + 255) / 256), 256, 0, stream>>>(Wmu_r, Wlv_r, w3);

  const int mblk = (N + 127) / 128;
  for (int k = 0; k < 5; ++k) {
    hipMemsetAsync(R1f, 0, (size_t)N * 512 * 4, stream);
    hipMemsetAsync(cntk, 0, (size_t)N * 4, stream);
    scatter1_kernel<<<dim3(E), 128, 0, stream>>>(x, ei, ea, R1f, cntk, E, k);
    mean_cvt_kernel<<<dim3((N * 512 / 4 + 255) / 256), 256, 0, stream>>>(R1f, cntk, meanb, N * 512 / 4);
    gemm_kernel<0><<<dim3(mblk, 4, 1), 256, 0, stream>>>(
        meanb, xb, w1 + (size_t)k * 512 * 1024, hb, nullptr,
        bl5, rmean, rvar, gamma, beta, k * 512, N);
  }

  gemm_kernel<1><<<dim3(mblk, 4, 1), 256, 0, stream>>>(
      hb, nullptr, w2, nullptr, zbuf,
      nullptr, nullptr, nullptr, nullptr, nullptr, 0, N);

  hipMemsetAsync(agg2, 0, (size_t)N * 512 * 4, stream);
  hipMemsetAsync(deg, 0, (size_t)N * 4, stream);
  scatter2_kernel<<<dim3(E), 128, 0, stream>>>(zbuf, ei, agg2, deg, E);

  gemm_kernel<2><<<dim3(mblk, 4, 1), 256, 0, stream>>>(
      hb, nullptr, w3, nullptr, (float*)d_out,
      agg2, deg, bmu, blv, nullptr, 0, N);
}

// Round 4
// 573.017 us; speedup vs baseline: 3.3542x; 3.3542x over previous
//
#include <hip/hip_runtime.h>
#include <stdint.h>

#define INCH 512
#define HIDW 512
#define CATW 2560
#define OUTW 256
#define BN_EPS 1e-5f
#define TS 1024   // scan tile

typedef __bf16 bf16x8 __attribute__((ext_vector_type(8)));
typedef float f32x4 __attribute__((ext_vector_type(4)));

__device__ __forceinline__ unsigned short f2bf(float f) {
  union { float f; unsigned u; } v; v.f = f;
  unsigned r = v.u + 0x7FFFu + ((v.u >> 16) & 1u);   // RNE
  return (unsigned short)(r >> 16);
}

__device__ __forceinline__ void pack4(unsigned short* dst, float a, float b, float c, float d) {
  unsigned lo = (unsigned)f2bf(a) | ((unsigned)f2bf(b) << 16);
  unsigned hi = (unsigned)f2bf(c) | ((unsigned)f2bf(d) << 16);
  *reinterpret_cast<uint2*>(dst) = make_uint2(lo, hi);
}

// ---------------- conversion / packing kernels ----------------

__global__ void cvt_bf16_kernel(const float* __restrict__ in, unsigned short* __restrict__ out, int n4) {
  int g = blockIdx.x * blockDim.x + threadIdx.x;
  if (g >= n4) return;
  int base = g * 4;
  float4 v = *reinterpret_cast<const float4*>(in + base);
  pack4(out + base, v.x, v.y, v.z, v.w);
}

__global__ void pack_w1_kernel(const float* __restrict__ Wl, const float* __restrict__ Wr,
                               unsigned short* __restrict__ out) {
  int g = blockIdx.x * blockDim.x + threadIdx.x;
  int base = g * 4;
  if (base >= 5 * 512 * 1024) return;
  int zj = base >> 10;
  int kk = base & 1023;
  const float* src = (kk < 512) ? (Wl + (size_t)zj * 512 + kk)
                                : (Wr + (size_t)zj * 512 + (kk - 512));
  float4 v = *reinterpret_cast<const float4*>(src);
  pack4(out + base, v.x, v.y, v.z, v.w);
}

__global__ void pack_lr_kernel(const float* __restrict__ Wa, const float* __restrict__ Wb,
                               unsigned short* __restrict__ out) {
  int g = blockIdx.x * blockDim.x + threadIdx.x;
  int base = g * 4;
  if (base >= 512 * CATW) return;
  int j2 = base / CATW;
  int c = base % CATW;
  const float* src = (j2 < OUTW) ? (Wa + (size_t)j2 * CATW + c)
                                 : (Wb + (size_t)(j2 - OUTW) * CATW + c);
  float4 v = *reinterpret_cast<const float4*>(src);
  pack4(out + base, v.x, v.y, v.z, v.w);
}

// ---------------- CSR build: key = dst*5 + rel ----------------

__global__ void hist_kernel(const int* __restrict__ ei, const int* __restrict__ ea,
                            int* __restrict__ cnt, int E) {
  int e = blockIdx.x * 256 + threadIdx.x;
  if (e >= E) return;
  atomicAdd(&cnt[ei[E + e] * 5 + ea[e]], 1);
}

// exclusive scan, tile = 1024 (256 thr x 4)
__global__ void scan1_kernel(const int* __restrict__ in, int* __restrict__ out,
                             int* __restrict__ bsum, int n) {
  __shared__ int lds[256];
  int t = threadIdx.x;
  int base = blockIdx.x * TS + t * 4;
  int4 v = make_int4(0, 0, 0, 0);
  if (base + 3 < n) v = *reinterpret_cast<const int4*>(in + base);
  else {
    if (base < n) v.x = in[base];
    if (base + 1 < n) v.y = in[base + 1];
    if (base + 2 < n) v.z = in[base + 2];
    if (base + 3 < n) v.w = in[base + 3];
  }
  int s = v.x + v.y + v.z + v.w;
  lds[t] = s;
  __syncthreads();
  for (int o = 1; o < 256; o <<= 1) {
    int a = (t >= o) ? lds[t - o] : 0;
    __syncthreads();
    lds[t] += a;
    __syncthreads();
  }
  int excl = lds[t] - s;
  if (t == 255) bsum[blockIdx.x] = lds[255];
  int e0 = excl, e1 = e0 + v.x, e2 = e1 + v.y, e3 = e2 + v.z;
  if (base < n) out[base] = e0;
  if (base + 1 < n) out[base + 1] = e1;
  if (base + 2 < n) out[base + 2] = e2;
  if (base + 3 < n) out[base + 3] = e3;
}

__global__ void scan2_kernel(int* __restrict__ bsum, int nb) {   // nb <= 128
  __shared__ int lds[128];
  int t = threadIdx.x;
  int v = (t < nb) ? bsum[t] : 0;
  lds[t] = v;
  __syncthreads();
  for (int o = 1; o < 128; o <<= 1) {
    int a = (t >= o) ? lds[t - o] : 0;
    __syncthreads();
    lds[t] += a;
    __syncthreads();
  }
  if (t < nb) bsum[t] = lds[t] - v;   // exclusive
}

__global__ void scan3_kernel(int* __restrict__ out, const int* __restrict__ bsum,
                             int n, int total) {
  int g = blockIdx.x * 256 + threadIdx.x;
  if (g == 0) out[n] = total;
  int base = g * 4;
  if (base >= n) return;
  int add = bsum[base / TS];
  if (base + 3 < n) {
    int4 v = *reinterpret_cast<int4*>(out + base);
    v.x += add; v.y += add; v.z += add; v.w += add;
    *reinterpret_cast<int4*>(out + base) = v;
  } else {
    for (int q = 0; q < 4 && base + q < n; ++q) out[base + q] += add;
  }
}

__global__ void fill_kernel(const int* __restrict__ ei, const int* __restrict__ ea,
                            const int* __restrict__ offs, int* __restrict__ fillc,
                            int* __restrict__ perm, int E) {
  int e = blockIdx.x * 256 + threadIdx.x;
  if (e >= E) return;
  int key = ei[E + e] * 5 + ea[e];
  int p = atomicAdd(&fillc[key], 1);
  perm[offs[key] + p] = ei[e];   // store src
}

// ---------------- gather kernels (no atomics) ----------------

// per relation: block i sums x[src] over segment (i*5+k), writes bf16 mean
__global__ void gather1_kernel(const float* __restrict__ x, const int* __restrict__ offs,
                               const int* __restrict__ perm, unsigned short* __restrict__ meanb,
                               int k) {
  int i = blockIdx.x;
  int t = threadIdx.x;
  int b0 = offs[i * 5 + k], b1 = offs[i * 5 + k + 1];
  float4 acc = make_float4(0.f, 0.f, 0.f, 0.f);
  for (int e = b0; e < b1; ++e) {
    int s = perm[e];
    float4 v = reinterpret_cast<const float4*>(x + (size_t)s * INCH)[t];
    acc.x += v.x; acc.y += v.y; acc.z += v.z; acc.w += v.w;
  }
  float inv = (b1 > b0) ? 1.0f / (float)(b1 - b0) : 0.0f;
  pack4(meanb + (size_t)i * 512 + t * 4, acc.x * inv, acc.y * inv, acc.z * inv, acc.w * inv);
}

// block i sums z[src] over segments [i*5, i*5+5), writes f32 mean
__global__ void gather2_kernel(const float* __restrict__ z, const int* __restrict__ offs,
                               const int* __restrict__ perm, float* __restrict__ mean2) {
  int i = blockIdx.x;
  int t = threadIdx.x;
  int b0 = offs[i * 5], b1 = offs[i * 5 + 5];
  float4 acc = make_float4(0.f, 0.f, 0.f, 0.f);
  for (int e = b0; e < b1; ++e) {
    int s = perm[e];
    float4 v = reinterpret_cast<const float4*>(z + (size_t)s * 512)[t];
    acc.x += v.x; acc.y += v.y; acc.z += v.z; acc.w += v.w;
  }
  float inv = (b1 > b0) ? 1.0f / (float)(b1 - b0) : 1.0f;
  reinterpret_cast<float4*>(mean2 + (size_t)i * 512)[t] =
      make_float4(acc.x * inv, acc.y * inv, acc.z * inv, acc.w * inv);
}

// ---------------- MFMA GEMM ----------------
// C[i][j] = sum_k A[i][k] * B[j][k]   (B row-major, K contiguous)
// MODE 0: A = [meanb_k | xb] (both [N,512], K=1024), B = w1+k*512*1024,
//         epilogue bias -> ReLU -> BN -> hb[i][zoff+j] (bf16)
// MODE 1: A = hb (K=2560), B = w2, epilogue raw f32 -> zbuf [N,512]
// MODE 2: A = hb (K=2560), B = w3, epilogue + mean2 + bias -> d_out
template<int MODE>
__global__ __launch_bounds__(256, 2)
void gemm_kernel(const unsigned short* __restrict__ A,
                 const unsigned short* __restrict__ A2,
                 const unsigned short* __restrict__ B,
                 unsigned short* __restrict__ hOut,
                 float* __restrict__ fOut,
                 const float* __restrict__ p0,   // MODE0: bl5   MODE2: mean2
                 const float* __restrict__ p1,   // MODE0: rmean
                 const float* __restrict__ p2,   // MODE0: rvar  MODE2: bmu
                 const float* __restrict__ p3,   // MODE0: gamma MODE2: blv
                 const float* __restrict__ p4,   // MODE0: beta
                 int zoff, int M)
{
  constexpr int KTOT = (MODE == 0) ? (2 * INCH) : CATW;
  constexpr int KT = KTOT / 32;

  const int rowBase = blockIdx.x * 128;
  const int nBase = blockIdx.y * 128;

  __shared__ uint4 As[512];
  __shared__ uint4 Bs[512];

  const int tid = threadIdx.x;
  const int lane = tid & 63;
  const int wave = tid >> 6;
  const int wr = wave >> 1, wc = wave & 1;
  const int lr = lane & 15, kg = lane >> 4;

  const int skg = tid & 3;
  const int sr = tid >> 2;                              // 0..63
  const int pA0 = skg * 128 + (sr ^ (skg << 1));        // XOR swizzle
  const int pA1 = skg * 128 + ((sr + 64) ^ (skg << 1));

  int ga0 = rowBase + sr;      if (ga0 >= M) ga0 = M - 1;
  int ga1 = rowBase + sr + 64; if (ga1 >= M) ga1 = M - 1;
  const size_t gb0 = (size_t)(nBase + sr) * KTOT;
  const size_t gb1 = (size_t)(nBase + sr + 64) * KTOT;

  int aslot[4], bslot[4];
#pragma unroll
  for (int m = 0; m < 4; ++m) {
    int r = wr * 64 + m * 16 + lr;
    aslot[m] = kg * 128 + (r ^ (kg << 1));
    int c = wc * 64 + m * 16 + lr;
    bslot[m] = kg * 128 + (c ^ (kg << 1));
  }

  f32x4 acc[4][4] = {};

  auto loadA = [&](int kt, int grow) -> uint4 {
    const int kk = kt * 32 + skg * 8;
    const unsigned short* s;
    if (MODE == 0) {
      if (kk < INCH) s = A + (size_t)grow * INCH + kk;
      else           s = A2 + (size_t)grow * INCH + (kk - INCH);
    } else {
      s = A + (size_t)grow * CATW + kk;
    }
    return *reinterpret_cast<const uint4*>(s);
  };
  auto loadB = [&](int kt, size_t gb) -> uint4 {
    const int kk = kt * 32 + skg * 8;
    return *reinterpret_cast<const uint4*>(B + gb + kk);
  };

  uint4 ra0 = loadA(0, ga0), ra1 = loadA(0, ga1);
  uint4 rb0 = loadB(0, gb0), rb1 = loadB(0, gb1);

  for (int kt = 0; kt < KT; ++kt) {
    __syncthreads();
    As[pA0] = ra0; As[pA1] = ra1;
    Bs[pA0] = rb0; Bs[pA1] = rb1;
    __syncthreads();
    if (kt + 1 < KT) {
      ra0 = loadA(kt + 1, ga0); ra1 = loadA(kt + 1, ga1);
      rb0 = loadB(kt + 1, gb0); rb1 = loadB(kt + 1, gb1);
    }
    bf16x8 af[4], bfv[4];
#pragma unroll
    for (int m = 0; m < 4; ++m) af[m] = *reinterpret_cast<const bf16x8*>(&As[aslot[m]]);
#pragma unroll
    for (int n = 0; n < 4; ++n) bfv[n] = *reinterpret_cast<const bf16x8*>(&Bs[bslot[n]]);
#pragma unroll
    for (int m = 0; m < 4; ++m)
#pragma unroll
      for (int n = 0; n < 4; ++n)
        acc[m][n] = __builtin_amdgcn_mfma_f32_16x16x32_bf16(af[m], bfv[n], acc[m][n], 0, 0, 0);
  }

#pragma unroll
  for (int n = 0; n < 4; ++n) {
    const int j = nBase + wc * 64 + n * 16 + lr;
    if (MODE == 0) {
      const int ch = zoff + j;
      const float bias = p0[ch];
      const float scale = rsqrtf(p2[ch] + BN_EPS) * p3[ch];
      const float rm = p1[ch], be = p4[ch];
#pragma unroll
      for (int m = 0; m < 4; ++m) {
        const int ib = rowBase + wr * 64 + m * 16 + kg * 4;
#pragma unroll
        for (int rr = 0; rr < 4; ++rr) {
          const int i = ib + rr;
          if (i < M) {
            float v = acc[m][n][rr] + bias;   // SAGE output
            v = fmaxf(v, 0.0f);               // ReLU FIRST (reference order)
            v = (v - rm) * scale + be;        // BN SECOND
            hOut[(size_t)i * CATW + ch] = f2bf(v);
          }
        }
      }
    } else if (MODE == 1) {
#pragma unroll
      for (int m = 0; m < 4; ++m) {
        const int ib = rowBase + wr * 64 + m * 16 + kg * 4;
#pragma unroll
        for (int rr = 0; rr < 4; ++rr) {
          const int i = ib + rr;
          if (i < M) fOut[(size_t)i * 512 + j] = acc[m][n][rr];
        }
      }
    } else {
      const float bias = (j < OUTW) ? p2[j] : p3[j - OUTW];
#pragma unroll
      for (int m = 0; m < 4; ++m) {
        const int ib = rowBase + wr * 64 + m * 16 + kg * 4;
#pragma unroll
        for (int rr = 0; rr < 4; ++rr) {
          const int i = ib + rr;
          if (i < M) {
            const float v = acc[m][n][rr] + p0[(size_t)i * 512 + j] + bias;
            size_t o = (j < OUTW) ? ((size_t)i * OUTW + j)
                                  : ((size_t)M * OUTW + (size_t)i * OUTW + (j - OUTW));
            fOut[o] = v;
          }
        }
      }
    }
  }
}

// ---------------- launch ----------------

extern "C" void kernel_launch(void* const* d_in, const int* in_sizes, int n_in,
                              void* d_out, int out_size, void* d_ws, size_t ws_size,
                              hipStream_t stream) {
  const float* x     = (const float*)d_in[0];
  const int*   ei    = (const int*)d_in[1];
  const int*   ea    = (const int*)d_in[2];
  const float* Wl5   = (const float*)d_in[3];
  const float* Wr5   = (const float*)d_in[4];
  const float* bl5   = (const float*)d_in[5];
  const float* Wmu_l = (const float*)d_in[6];
  const float* Wmu_r = (const float*)d_in[7];
  const float* bmu   = (const float*)d_in[8];
  const float* Wlv_l = (const float*)d_in[9];
  const float* Wlv_r = (const float*)d_in[10];
  const float* blv   = (const float*)d_in[11];
  const float* gamma = (const float*)d_in[12];
  const float* beta  = (const float*)d_in[13];
  const float* rmean = (const float*)d_in[14];
  const float* rvar  = (const float*)d_in[15];
  (void)n_in; (void)out_size;

  const int N = in_sizes[0] / INCH;   // 20000
  const int E = in_sizes[2];          // 100000
  const int NKEY = N * 5;             // 100000 CSR segments

  // ---- workspace layout (~202 MB) ----
  char* ws = (char*)d_ws;
  size_t off = 0;
  auto take = [&](size_t bytes) { char* p = ws + off; off += (bytes + 255) & ~(size_t)255; return p; };
  unsigned short* hb = (unsigned short*)take((size_t)N * CATW * 2);   // 102.4 MB
  float* R1f = (float*)take((size_t)N * 512 * 4);                     // 41 MB: mean2
  char*  R2  = take((size_t)N * 512 * 4);                             // 41 MB: meanb|xb, later zbuf
  unsigned short* w1 = (unsigned short*)take((size_t)5 * 512 * 1024 * 2);
  unsigned short* w2 = (unsigned short*)take((size_t)512 * CATW * 2);
  unsigned short* w3 = (unsigned short*)take((size_t)512 * CATW * 2);
  int* cntk  = (int*)take((size_t)NKEY * 4);
  int* offs  = (int*)take((size_t)(NKEY + 1) * 4);
  int* fillc = (int*)take((size_t)NKEY * 4);
  int* perm  = (int*)take((size_t)E * 4);
  int* bsum  = (int*)take(256 * 4);
  if (off > ws_size) return;  // diagnostic guard

  unsigned short* meanb = (unsigned short*)R2;                   // [N,512] bf16
  unsigned short* xb    = (unsigned short*)(R2 + (size_t)N * 512 * 2);
  float* zbuf = (float*)R2;                                      // [N,512] f32 (after layer-1)
  float* mean2 = R1f;

  // weight packing + x conversion
  cvt_bf16_kernel<<<dim3((N * INCH / 4 + 255) / 256), 256, 0, stream>>>(x, xb, N * INCH / 4);
  pack_w1_kernel<<<dim3((5 * 512 * 1024 / 4 + 255) / 256), 256, 0, stream>>>(Wl5, Wr5, w1);
  pack_lr_kernel<<<dim3((512 * CATW / 4 + 255) / 256), 256, 0, stream>>>(Wmu_l, Wlv_l, w2);
  pack_lr_kernel<<<dim3((512 * CATW / 4 + 255) / 256), 256, 0, stream>>>(Wmu_r, Wlv_r, w3);

  // CSR build: key = dst*5 + rel
  hipMemsetAsync(cntk, 0, (size_t)NKEY * 4, stream);
  hipMemsetAsync(fillc, 0, (size_t)NKEY * 4, stream);
  hist_kernel<<<dim3((E + 255) / 256), 256, 0, stream>>>(ei, ea, cntk, E);
  const int nb = (NKEY + TS - 1) / TS;   // 98 (<=128 required by scan2)
  scan1_kernel<<<dim3(nb), 256, 0, stream>>>(cntk, offs, bsum, NKEY);
  scan2_kernel<<<dim3(1), 128, 0, stream>>>(bsum, nb);
  scan3_kernel<<<dim3((NKEY / 4 + 255) / 256 + 1), 256, 0, stream>>>(offs, bsum, NKEY, E);
  fill_kernel<<<dim3((E + 255) / 256), 256, 0, stream>>>(ei, ea, offs, fillc, perm, E);

  // layer 1: per relation gather -> GEMM (bias -> ReLU -> BN fused)
  const int mblk = (N + 127) / 128;
  for (int k = 0; k < 5; ++k) {
    gather1_kernel<<<dim3(N), 128, 0, stream>>>(x, offs, perm, meanb, k);
    gemm_kernel<0><<<dim3(mblk, 4, 1), 256, 0, stream>>>(
        meanb, xb, w1 + (size_t)k * 512 * 1024, hb, nullptr,
        bl5, rmean, rvar, gamma, beta, k * 512, N);
  }

  // layer 2: z = hb @ w2^T ; mean2 = segment-mean(z) ; out = hb @ w3^T + mean2 + bias
  gemm_kernel<1><<<dim3(mblk, 4, 1), 256, 0, stream>>>(
      hb, nullptr, w2, nullptr, zbuf,
      nullptr, nullptr, nullptr, nullptr, nullptr, 0, N);

  gather2_kernel<<<dim3(N), 128, 0, stream>>>(zbuf, offs, perm, mean2);

  gemm_kernel<2><<<dim3(mblk, 4, 1), 256, 0, stream>>>(
      hb, nullptr, w3, nullptr, (float*)d_out,
      mean2, nullptr, bmu, blv, nullptr, 0, N);
}

// Round 5
// 497.816 us; speedup vs baseline: 3.8609x; 1.1511x over previous
//
#include <hip/hip_runtime.h>
#include <stdint.h>

#define INCH 512
#define HIDW 512
#define CATW 2560
#define OUTW 256
#define BN_EPS 1e-5f
#define TS 1024   // scan tile

typedef __bf16 bf16x8 __attribute__((ext_vector_type(8)));
typedef float f32x4 __attribute__((ext_vector_type(4)));

__device__ __forceinline__ unsigned short f2bf(float f) {
  union { float f; unsigned u; } v; v.f = f;
  unsigned r = v.u + 0x7FFFu + ((v.u >> 16) & 1u);   // RNE
  return (unsigned short)(r >> 16);
}

__device__ __forceinline__ void pack4(unsigned short* dst, float a, float b, float c, float d) {
  unsigned lo = (unsigned)f2bf(a) | ((unsigned)f2bf(b) << 16);
  unsigned hi = (unsigned)f2bf(c) | ((unsigned)f2bf(d) << 16);
  *reinterpret_cast<uint2*>(dst) = make_uint2(lo, hi);
}

// ---------------- conversion / packing kernels ----------------

__global__ void cvt_bf16_kernel(const float* __restrict__ in, unsigned short* __restrict__ out, int n4) {
  int g = blockIdx.x * blockDim.x + threadIdx.x;
  if (g >= n4) return;
  int base = g * 4;
  float4 v = *reinterpret_cast<const float4*>(in + base);
  pack4(out + base, v.x, v.y, v.z, v.w);
}

__global__ void pack_w1_kernel(const float* __restrict__ Wl, const float* __restrict__ Wr,
                               unsigned short* __restrict__ out) {
  int g = blockIdx.x * blockDim.x + threadIdx.x;
  int base = g * 4;
  if (base >= 5 * 512 * 1024) return;
  int zj = base >> 10;
  int kk = base & 1023;
  const float* src = (kk < 512) ? (Wl + (size_t)zj * 512 + kk)
                                : (Wr + (size_t)zj * 512 + (kk - 512));
  float4 v = *reinterpret_cast<const float4*>(src);
  pack4(out + base, v.x, v.y, v.z, v.w);
}

__global__ void pack_lr_kernel(const float* __restrict__ Wa, const float* __restrict__ Wb,
                               unsigned short* __restrict__ out) {
  int g = blockIdx.x * blockDim.x + threadIdx.x;
  int base = g * 4;
  if (base >= 512 * CATW) return;
  int j2 = base / CATW;
  int c = base % CATW;
  const float* src = (j2 < OUTW) ? (Wa + (size_t)j2 * CATW + c)
                                 : (Wb + (size_t)(j2 - OUTW) * CATW + c);
  float4 v = *reinterpret_cast<const float4*>(src);
  pack4(out + base, v.x, v.y, v.z, v.w);
}

// ---------------- CSR build: key = dst*5 + rel ----------------

__global__ void hist_kernel(const int* __restrict__ ei, const int* __restrict__ ea,
                            int* __restrict__ cnt, int E) {
  int e = blockIdx.x * 256 + threadIdx.x;
  if (e >= E) return;
  atomicAdd(&cnt[ei[E + e] * 5 + ea[e]], 1);
}

__global__ void scan1_kernel(const int* __restrict__ in, int* __restrict__ out,
                             int* __restrict__ bsum, int n) {
  __shared__ int lds[256];
  int t = threadIdx.x;
  int base = blockIdx.x * TS + t * 4;
  int4 v = make_int4(0, 0, 0, 0);
  if (base + 3 < n) v = *reinterpret_cast<const int4*>(in + base);
  else {
    if (base < n) v.x = in[base];
    if (base + 1 < n) v.y = in[base + 1];
    if (base + 2 < n) v.z = in[base + 2];
    if (base + 3 < n) v.w = in[base + 3];
  }
  int s = v.x + v.y + v.z + v.w;
  lds[t] = s;
  __syncthreads();
  for (int o = 1; o < 256; o <<= 1) {
    int a = (t >= o) ? lds[t - o] : 0;
    __syncthreads();
    lds[t] += a;
    __syncthreads();
  }
  int excl = lds[t] - s;
  if (t == 255) bsum[blockIdx.x] = lds[255];
  int e0 = excl, e1 = e0 + v.x, e2 = e1 + v.y, e3 = e2 + v.z;
  if (base < n) out[base] = e0;
  if (base + 1 < n) out[base + 1] = e1;
  if (base + 2 < n) out[base + 2] = e2;
  if (base + 3 < n) out[base + 3] = e3;
}

__global__ void scan2_kernel(int* __restrict__ bsum, int nb) {   // nb <= 128
  __shared__ int lds[128];
  int t = threadIdx.x;
  int v = (t < nb) ? bsum[t] : 0;
  lds[t] = v;
  __syncthreads();
  for (int o = 1; o < 128; o <<= 1) {
    int a = (t >= o) ? lds[t - o] : 0;
    __syncthreads();
    lds[t] += a;
    __syncthreads();
  }
  if (t < nb) bsum[t] = lds[t] - v;   // exclusive
}

__global__ void scan3_kernel(int* __restrict__ out, const int* __restrict__ bsum,
                             int n, int total) {
  int g = blockIdx.x * 256 + threadIdx.x;
  if (g == 0) out[n] = total;
  int base = g * 4;
  if (base >= n) return;
  int add = bsum[base / TS];
  if (base + 3 < n) {
    int4 v = *reinterpret_cast<int4*>(out + base);
    v.x += add; v.y += add; v.z += add; v.w += add;
    *reinterpret_cast<int4*>(out + base) = v;
  } else {
    for (int q = 0; q < 4 && base + q < n; ++q) out[base + q] += add;
  }
}

__global__ void fill_kernel(const int* __restrict__ ei, const int* __restrict__ ea,
                            const int* __restrict__ offs, int* __restrict__ fillc,
                            int* __restrict__ perm, int E) {
  int e = blockIdx.x * 256 + threadIdx.x;
  if (e >= E) return;
  int key = ei[E + e] * 5 + ea[e];
  int p = atomicAdd(&fillc[key], 1);
  perm[offs[key] + p] = ei[e];   // store src
}

// ---------------- gather kernels (no atomics) ----------------

__global__ void gather1_kernel(const float* __restrict__ x, const int* __restrict__ offs,
                               const int* __restrict__ perm, unsigned short* __restrict__ meanb,
                               int k) {
  int i = blockIdx.x;
  int t = threadIdx.x;
  int b0 = offs[i * 5 + k], b1 = offs[i * 5 + k + 1];
  float4 acc = make_float4(0.f, 0.f, 0.f, 0.f);
  for (int e = b0; e < b1; ++e) {
    int s = perm[e];
    float4 v = reinterpret_cast<const float4*>(x + (size_t)s * INCH)[t];
    acc.x += v.x; acc.y += v.y; acc.z += v.z; acc.w += v.w;
  }
  float inv = (b1 > b0) ? 1.0f / (float)(b1 - b0) : 0.0f;
  pack4(meanb + (size_t)i * 512 + t * 4, acc.x * inv, acc.y * inv, acc.z * inv, acc.w * inv);
}

__global__ void gather2_kernel(const float* __restrict__ z, const int* __restrict__ offs,
                               const int* __restrict__ perm, float* __restrict__ mean2) {
  int i = blockIdx.x;
  int t = threadIdx.x;
  int b0 = offs[i * 5], b1 = offs[i * 5 + 5];
  float4 acc = make_float4(0.f, 0.f, 0.f, 0.f);
  for (int e = b0; e < b1; ++e) {
    int s = perm[e];
    float4 v = reinterpret_cast<const float4*>(z + (size_t)s * 512)[t];
    acc.x += v.x; acc.y += v.y; acc.z += v.z; acc.w += v.w;
  }
  float inv = (b1 > b0) ? 1.0f / (float)(b1 - b0) : 1.0f;
  reinterpret_cast<float4*>(mean2 + (size_t)i * 512)[t] =
      make_float4(acc.x * inv, acc.y * inv, acc.z * inv, acc.w * inv);
}

// ---------------- MFMA GEMM (m97-style: global_load_lds + linear LDS) ----------------
// C[i][j] = sum_k A[i][k] * B[j][k]   (B row-major, K contiguous)
// 128x128 tile, BK=32, 4 waves, XCD-chunked tile swizzle (col-fastest per XCD).
template<int MODE>
__global__ __launch_bounds__(256, 3)
void gemm_kernel(const unsigned short* __restrict__ A,
                 const unsigned short* __restrict__ A2,
                 const unsigned short* __restrict__ B,
                 unsigned short* __restrict__ hOut,
                 float* __restrict__ fOut,
                 const float* __restrict__ p0,   // MODE0: bl5   MODE2: mean2
                 const float* __restrict__ p1,   // MODE0: rmean
                 const float* __restrict__ p2,   // MODE0: rvar  MODE2: bmu
                 const float* __restrict__ p3,   // MODE0: gamma MODE2: blv
                 const float* __restrict__ p4,   // MODE0: beta
                 int zoff, int M)
{
  constexpr int KTOT = (MODE == 0) ? (2 * INCH) : CATW;
  constexpr int KT = KTOT / 32;
  constexpr int NBLK = 4;   // 512 output cols / 128

  // ---- bijective XCD-chunked swizzle (m204): col index fastest within an XCD chunk
  {
  }
  const int nwg = gridDim.x;
  const int o = blockIdx.x;
  const int q = nwg >> 3, r = nwg & 7;
  const int xcd = o & 7;
  const int wg = (xcd < r ? xcd * (q + 1) : r * (q + 1) + (xcd - r) * q) + (o >> 3);
  const int rowBase = (wg / NBLK) * 128;
  const int nBase = (wg % NBLK) * 128;

  __shared__ unsigned short A_lds[4096];   // [128 rows][32 k] bf16, 8KB
  __shared__ unsigned short B_lds[4096];

  const int tid = threadIdx.x;
  const int lane = tid & 63;
  const int wv = tid >> 6;                 // 0..3
  const int wr = wv >> 1, wc = wv & 1;
  const int lr = lane & 15, kg = lane >> 4;

  // staging geometry: chunk c (0..7) = 16 rows x 32 k; wave wv stages chunks {2wv, 2wv+1}
  // lane l writes LDS bytes [c*1024 + l*16, +16) == row c*16+(l>>2), k (l&3)*8
  const int srow0 = (wv * 2) * 16 + (lane >> 2);       // chunk 2wv
  const int srow1 = (wv * 2 + 1) * 16 + (lane >> 2);   // chunk 2wv+1
  const int skoff = (lane & 3) * 8;
  int gar0 = rowBase + srow0; if (gar0 >= M) gar0 = M - 1;
  int gar1 = rowBase + srow1; if (gar1 >= M) gar1 = M - 1;
  const size_t gbr0 = (size_t)(nBase + srow0) * KTOT;
  const size_t gbr1 = (size_t)(nBase + srow1) * KTOT;
  unsigned short* ldsA0 = &A_lds[(wv * 2) * 512];
  unsigned short* ldsA1 = &A_lds[(wv * 2 + 1) * 512];
  unsigned short* ldsB0 = &B_lds[(wv * 2) * 512];
  unsigned short* ldsB1 = &B_lds[(wv * 2 + 1) * 512];

  int aslot[4], bslot[4];
#pragma unroll
  for (int m = 0; m < 4; ++m) {
    aslot[m] = (wr * 64 + m * 16 + lr) * 32 + kg * 8;
    bslot[m] = (wc * 64 + m * 16 + lr) * 32 + kg * 8;
  }

  f32x4 acc[4][4] = {};

  for (int kt = 0; kt < KT; ++kt) {
    const int kk0 = kt * 32;
    const unsigned short *a0, *a1;
    if (MODE == 0) {
      if (kk0 < INCH) {
        a0 = A + (size_t)gar0 * INCH + kk0 + skoff;
        a1 = A + (size_t)gar1 * INCH + kk0 + skoff;
      } else {
        a0 = A2 + (size_t)gar0 * INCH + (kk0 - INCH) + skoff;
        a1 = A2 + (size_t)gar1 * INCH + (kk0 - INCH) + skoff;
      }
    } else {
      a0 = A + (size_t)gar0 * KTOT + kk0 + skoff;
      a1 = A + (size_t)gar1 * KTOT + kk0 + skoff;
    }
    const unsigned short* b0 = B + gbr0 + kk0 + skoff;
    const unsigned short* b1 = B + gbr1 + kk0 + skoff;

    __syncthreads();   // previous tile fully consumed before overwrite
    __builtin_amdgcn_global_load_lds((const void*)a0, (void*)ldsA0, 16, 0, 0);
    __builtin_amdgcn_global_load_lds((const void*)a1, (void*)ldsA1, 16, 0, 0);
    __builtin_amdgcn_global_load_lds((const void*)b0, (void*)ldsB0, 16, 0, 0);
    __builtin_amdgcn_global_load_lds((const void*)b1, (void*)ldsB1, 16, 0, 0);
    __syncthreads();   // vmcnt(0) drain + barrier: staged tile visible

    bf16x8 af[4], bfv[4];
#pragma unroll
    for (int m = 0; m < 4; ++m) af[m] = *reinterpret_cast<const bf16x8*>(&A_lds[aslot[m]]);
#pragma unroll
    for (int n = 0; n < 4; ++n) bfv[n] = *reinterpret_cast<const bf16x8*>(&B_lds[bslot[n]]);
#pragma unroll
    for (int m = 0; m < 4; ++m)
#pragma unroll
      for (int n = 0; n < 4; ++n)
        acc[m][n] = __builtin_amdgcn_mfma_f32_16x16x32_bf16(af[m], bfv[n], acc[m][n], 0, 0, 0);
  }

#pragma unroll
  for (int n = 0; n < 4; ++n) {
    const int j = nBase + wc * 64 + n * 16 + lr;
    if (MODE == 0) {
      const int ch = zoff + j;
      const float bias = p0[ch];
      const float scale = rsqrtf(p2[ch] + BN_EPS) * p3[ch];
      const float rm = p1[ch], be = p4[ch];
#pragma unroll
      for (int m = 0; m < 4; ++m) {
        const int ib = rowBase + wr * 64 + m * 16 + kg * 4;
#pragma unroll
        for (int rr = 0; rr < 4; ++rr) {
          const int i = ib + rr;
          if (i < M) {
            float v = acc[m][n][rr] + bias;   // SAGE output
            v = fmaxf(v, 0.0f);               // ReLU FIRST (reference order)
            v = (v - rm) * scale + be;        // BN SECOND
            hOut[(size_t)i * CATW + ch] = f2bf(v);
          }
        }
      }
    } else if (MODE == 1) {
#pragma unroll
      for (int m = 0; m < 4; ++m) {
        const int ib = rowBase + wr * 64 + m * 16 + kg * 4;
#pragma unroll
        for (int rr = 0; rr < 4; ++rr) {
          const int i = ib + rr;
          if (i < M) fOut[(size_t)i * 512 + j] = acc[m][n][rr];
        }
      }
    } else {
      const float bias = (j < OUTW) ? p2[j] : p3[j - OUTW];
#pragma unroll
      for (int m = 0; m < 4; ++m) {
        const int ib = rowBase + wr * 64 + m * 16 + kg * 4;
#pragma unroll
        for (int rr = 0; rr < 4; ++rr) {
          const int i = ib + rr;
          if (i < M) {
            const float v = acc[m][n][rr] + p0[(size_t)i * 512 + j] + bias;
            size_t o2 = (j < OUTW) ? ((size_t)i * OUTW + j)
                                   : ((size_t)M * OUTW + (size_t)i * OUTW + (j - OUTW));
            fOut[o2] = v;
          }
        }
      }
    }
  }
}

// ---------------- launch ----------------

extern "C" void kernel_launch(void* const* d_in, const int* in_sizes, int n_in,
                              void* d_out, int out_size, void* d_ws, size_t ws_size,
                              hipStream_t stream) {
  const float* x     = (const float*)d_in[0];
  const int*   ei    = (const int*)d_in[1];
  const int*   ea    = (const int*)d_in[2];
  const float* Wl5   = (const float*)d_in[3];
  const float* Wr5   = (const float*)d_in[4];
  const float* bl5   = (const float*)d_in[5];
  const float* Wmu_l = (const float*)d_in[6];
  const float* Wmu_r = (const float*)d_in[7];
  const float* bmu   = (const float*)d_in[8];
  const float* Wlv_l = (const float*)d_in[9];
  const float* Wlv_r = (const float*)d_in[10];
  const float* blv   = (const float*)d_in[11];
  const float* gamma = (const float*)d_in[12];
  const float* beta  = (const float*)d_in[13];
  const float* rmean = (const float*)d_in[14];
  const float* rvar  = (const float*)d_in[15];
  (void)n_in; (void)out_size;

  const int N = in_sizes[0] / INCH;   // 20000
  const int E = in_sizes[2];          // 100000
  const int NKEY = N * 5;             // 100000 CSR segments

  // ---- workspace layout (~203 MB) ----
  char* ws = (char*)d_ws;
  size_t off = 0;
  auto take = [&](size_t bytes) { char* p = ws + off; off += (bytes + 255) & ~(size_t)255; return p; };
  unsigned short* hb = (unsigned short*)take((size_t)N * CATW * 2);   // 102.4 MB
  float* R1f = (float*)take((size_t)N * 512 * 4);                     // 41 MB: mean2
  char*  R2  = take((size_t)N * 512 * 4);                             // 41 MB: meanb|xb, later zbuf
  unsigned short* w1 = (unsigned short*)take((size_t)5 * 512 * 1024 * 2);
  unsigned short* w2 = (unsigned short*)take((size_t)512 * CATW * 2);
  unsigned short* w3 = (unsigned short*)take((size_t)512 * CATW * 2);
  int* cntk  = (int*)take((size_t)NKEY * 4);
  int* offs  = (int*)take((size_t)(NKEY + 1) * 4);
  int* fillc = (int*)take((size_t)NKEY * 4);
  int* perm  = (int*)take((size_t)E * 4);
  int* bsum  = (int*)take(256 * 4);
  if (off > ws_size) return;  // diagnostic guard

  unsigned short* meanb = (unsigned short*)R2;                   // [N,512] bf16
  unsigned short* xb    = (unsigned short*)(R2 + (size_t)N * 512 * 2);
  float* zbuf = (float*)R2;                                      // [N,512] f32 (after layer-1)
  float* mean2 = R1f;

  // weight packing + x conversion
  cvt_bf16_kernel<<<dim3((N * INCH / 4 + 255) / 256), 256, 0, stream>>>(x, xb, N * INCH / 4);
  pack_w1_kernel<<<dim3((5 * 512 * 1024 / 4 + 255) / 256), 256, 0, stream>>>(Wl5, Wr5, w1);
  pack_lr_kernel<<<dim3((512 * CATW / 4 + 255) / 256), 256, 0, stream>>>(Wmu_l, Wlv_l, w2);
  pack_lr_kernel<<<dim3((512 * CATW / 4 + 255) / 256), 256, 0, stream>>>(Wmu_r, Wlv_r, w3);

  // CSR build: key = dst*5 + rel
  hipMemsetAsync(cntk, 0, (size_t)NKEY * 4, stream);
  hipMemsetAsync(fillc, 0, (size_t)NKEY * 4, stream);
  hist_kernel<<<dim3((E + 255) / 256), 256, 0, stream>>>(ei, ea, cntk, E);
  const int nb = (NKEY + TS - 1) / TS;   // 98 (<=128 required by scan2)
  scan1_kernel<<<dim3(nb), 256, 0, stream>>>(cntk, offs, bsum, NKEY);
  scan2_kernel<<<dim3(1), 128, 0, stream>>>(bsum, nb);
  scan3_kernel<<<dim3((NKEY / 4 + 255) / 256 + 1), 256, 0, stream>>>(offs, bsum, NKEY, E);
  fill_kernel<<<dim3((E + 255) / 256), 256, 0, stream>>>(ei, ea, offs, fillc, perm, E);

  // layer 1: per relation gather -> GEMM (bias -> ReLU -> BN fused)
  const int mblk = (N + 127) / 128;
  const int tiles = mblk * 4;
  for (int k = 0; k < 5; ++k) {
    gather1_kernel<<<dim3(N), 128, 0, stream>>>(x, offs, perm, meanb, k);
    gemm_kernel<0><<<dim3(tiles), 256, 0, stream>>>(
        meanb, xb, w1 + (size_t)k * 512 * 1024, hb, nullptr,
        bl5, rmean, rvar, gamma, beta, k * 512, N);
  }

  // layer 2: z = hb @ w2^T ; mean2 = segment-mean(z) ; out = hb @ w3^T + mean2 + bias
  gemm_kernel<1><<<dim3(tiles), 256, 0, stream>>>(
      hb, nullptr, w2, nullptr, zbuf,
      nullptr, nullptr, nullptr, nullptr, nullptr, 0, N);

  gather2_kernel<<<dim3(N), 128, 0, stream>>>(zbuf, offs, perm, mean2);

  gemm_kernel<2><<<dim3(tiles), 256, 0, stream>>>(
      hb, nullptr, w3, nullptr, (float*)d_out,
      mean2, nullptr, bmu, blv, nullptr, 0, N);
}

// Round 6
// 444.000 us; speedup vs baseline: 4.3289x; 1.1212x over previous
//
#include <hip/hip_runtime.h>
#include <stdint.h>

#define INCH 512
#define HIDW 512
#define CATW 2560
#define OUTW 256
#define BN_EPS 1e-5f
#define TS 1024   // scan tile

typedef __bf16 bf16x8 __attribute__((ext_vector_type(8)));
typedef float f32x4 __attribute__((ext_vector_type(4)));

__device__ __forceinline__ unsigned short f2bf(float f) {
  union { float f; unsigned u; } v; v.f = f;
  unsigned r = v.u + 0x7FFFu + ((v.u >> 16) & 1u);   // RNE
  return (unsigned short)(r >> 16);
}

__device__ __forceinline__ float bf2f(unsigned short u) {
  union { unsigned u; float f; } v; v.u = ((unsigned)u) << 16; return v.f;
}

__device__ __forceinline__ void pack4(unsigned short* dst, float a, float b, float c, float d) {
  unsigned lo = (unsigned)f2bf(a) | ((unsigned)f2bf(b) << 16);
  unsigned hi = (unsigned)f2bf(c) | ((unsigned)f2bf(d) << 16);
  *reinterpret_cast<uint2*>(dst) = make_uint2(lo, hi);
}

// ---------------- conversion / packing kernels ----------------

__global__ void cvt_bf16_kernel(const float* __restrict__ in, unsigned short* __restrict__ out, int n4) {
  int g = blockIdx.x * blockDim.x + threadIdx.x;
  if (g >= n4) return;
  int base = g * 4;
  float4 v = *reinterpret_cast<const float4*>(in + base);
  pack4(out + base, v.x, v.y, v.z, v.w);
}

__global__ void pack_w1_kernel(const float* __restrict__ Wl, const float* __restrict__ Wr,
                               unsigned short* __restrict__ out) {
  int g = blockIdx.x * blockDim.x + threadIdx.x;
  int base = g * 4;
  if (base >= 5 * 512 * 1024) return;
  int zj = base >> 10;
  int kk = base & 1023;
  const float* src = (kk < 512) ? (Wl + (size_t)zj * 512 + kk)
                                : (Wr + (size_t)zj * 512 + (kk - 512));
  float4 v = *reinterpret_cast<const float4*>(src);
  pack4(out + base, v.x, v.y, v.z, v.w);
}

__global__ void pack_lr_kernel(const float* __restrict__ Wa, const float* __restrict__ Wb,
                               unsigned short* __restrict__ out) {
  int g = blockIdx.x * blockDim.x + threadIdx.x;
  int base = g * 4;
  if (base >= 512 * CATW) return;
  int j2 = base / CATW;
  int c = base % CATW;
  const float* src = (j2 < OUTW) ? (Wa + (size_t)j2 * CATW + c)
                                 : (Wb + (size_t)(j2 - OUTW) * CATW + c);
  float4 v = *reinterpret_cast<const float4*>(src);
  pack4(out + base, v.x, v.y, v.z, v.w);
}

// ---------------- CSR build: key = dst*5 + rel ----------------

__global__ void hist_kernel(const int* __restrict__ ei, const int* __restrict__ ea,
                            int* __restrict__ cnt, int E) {
  int e = blockIdx.x * 256 + threadIdx.x;
  if (e >= E) return;
  atomicAdd(&cnt[ei[E + e] * 5 + ea[e]], 1);
}

__global__ void scan1_kernel(const int* __restrict__ in, int* __restrict__ out,
                             int* __restrict__ bsum, int n) {
  __shared__ int lds[256];
  int t = threadIdx.x;
  int base = blockIdx.x * TS + t * 4;
  int4 v = make_int4(0, 0, 0, 0);
  if (base + 3 < n) v = *reinterpret_cast<const int4*>(in + base);
  else {
    if (base < n) v.x = in[base];
    if (base + 1 < n) v.y = in[base + 1];
    if (base + 2 < n) v.z = in[base + 2];
    if (base + 3 < n) v.w = in[base + 3];
  }
  int s = v.x + v.y + v.z + v.w;
  lds[t] = s;
  __syncthreads();
  for (int o = 1; o < 256; o <<= 1) {
    int a = (t >= o) ? lds[t - o] : 0;
    __syncthreads();
    lds[t] += a;
    __syncthreads();
  }
  int excl = lds[t] - s;
  if (t == 255) bsum[blockIdx.x] = lds[255];
  int e0 = excl, e1 = e0 + v.x, e2 = e1 + v.y, e3 = e2 + v.z;
  if (base < n) out[base] = e0;
  if (base + 1 < n) out[base + 1] = e1;
  if (base + 2 < n) out[base + 2] = e2;
  if (base + 3 < n) out[base + 3] = e3;
}

__global__ void scan2_kernel(int* __restrict__ bsum, int nb) {   // nb <= 128
  __shared__ int lds[128];
  int t = threadIdx.x;
  int v = (t < nb) ? bsum[t] : 0;
  lds[t] = v;
  __syncthreads();
  for (int o = 1; o < 128; o <<= 1) {
    int a = (t >= o) ? lds[t - o] : 0;
    __syncthreads();
    lds[t] += a;
    __syncthreads();
  }
  if (t < nb) bsum[t] = lds[t] - v;   // exclusive
}

__global__ void scan3_kernel(int* __restrict__ out, const int* __restrict__ bsum,
                             int n, int total) {
  int g = blockIdx.x * 256 + threadIdx.x;
  if (g == 0) out[n] = total;
  int base = g * 4;
  if (base >= n) return;
  int add = bsum[base / TS];
  if (base + 3 < n) {
    int4 v = *reinterpret_cast<int4*>(out + base);
    v.x += add; v.y += add; v.z += add; v.w += add;
    *reinterpret_cast<int4*>(out + base) = v;
  } else {
    for (int q = 0; q < 4 && base + q < n; ++q) out[base + q] += add;
  }
}

__global__ void fill_kernel(const int* __restrict__ ei, const int* __restrict__ ea,
                            const int* __restrict__ offs, int* __restrict__ fillc,
                            int* __restrict__ perm, int E) {
  int e = blockIdx.x * 256 + threadIdx.x;
  if (e >= E) return;
  int key = ei[E + e] * 5 + ea[e];
  int p = atomicAdd(&fillc[key], 1);
  perm[offs[key] + p] = ei[e];   // store src
}

// ---------------- gather kernels (no atomics) ----------------

// block (i,k): mean of xb[src] over segment i*5+k -> meanb5[i][k*512..]
__global__ void gather1_kernel(const unsigned short* __restrict__ xb, const int* __restrict__ offs,
                               const int* __restrict__ perm, unsigned short* __restrict__ meanb5) {
  int i = blockIdx.x;
  int k = blockIdx.y;
  int t = threadIdx.x;
  int b0 = offs[i * 5 + k], b1 = offs[i * 5 + k + 1];
  float a0 = 0.f, a1 = 0.f, a2 = 0.f, a3 = 0.f;
  for (int e = b0; e < b1; ++e) {
    int s = perm[e];
    ushort4 v = reinterpret_cast<const ushort4*>(xb + (size_t)s * 512)[t];
    a0 += bf2f(v.x); a1 += bf2f(v.y); a2 += bf2f(v.z); a3 += bf2f(v.w);
  }
  float inv = (b1 > b0) ? 1.0f / (float)(b1 - b0) : 0.0f;
  pack4(meanb5 + (size_t)i * CATW + k * 512 + t * 4, a0 * inv, a1 * inv, a2 * inv, a3 * inv);
}

__global__ void gather2_kernel(const float* __restrict__ z, const int* __restrict__ offs,
                               const int* __restrict__ perm, float* __restrict__ mean2) {
  int i = blockIdx.x;
  int t = threadIdx.x;
  int b0 = offs[i * 5], b1 = offs[i * 5 + 5];
  float4 acc = make_float4(0.f, 0.f, 0.f, 0.f);
  for (int e = b0; e < b1; ++e) {
    int s = perm[e];
    float4 v = reinterpret_cast<const float4*>(z + (size_t)s * 512)[t];
    acc.x += v.x; acc.y += v.y; acc.z += v.z; acc.w += v.w;
  }
  float inv = (b1 > b0) ? 1.0f / (float)(b1 - b0) : 1.0f;
  reinterpret_cast<float4*>(mean2 + (size_t)i * 512)[t] =
      make_float4(acc.x * inv, acc.y * inv, acc.z * inv, acc.w * inv);
}

// d_out += mean2 + bias   (mu half / logvar half)
__global__ void add_kernel(float* __restrict__ dout, const float* __restrict__ mean2,
                           const float* __restrict__ bmu, const float* __restrict__ blv,
                           int M, int n4) {
  int g = blockIdx.x * 256 + threadIdx.x;
  if (g >= n4) return;
  int base = g * 4;
  int i = base >> 9;
  int c = base & 511;
  float4 m2 = *reinterpret_cast<const float4*>(mean2 + (size_t)i * 512 + c);
  int cc = c & 255;
  float* op;
  const float* bp;
  if (c < 256) { op = dout + (size_t)i * OUTW + cc; bp = bmu + cc; }
  else         { op = dout + (size_t)M * OUTW + (size_t)i * OUTW + cc; bp = blv + cc; }
  float4 y = *reinterpret_cast<float4*>(op);
  float4 b = *reinterpret_cast<const float4*>(bp);
  y.x += m2.x + b.x; y.y += m2.y + b.y; y.z += m2.z + b.z; y.w += m2.w + b.w;
  *reinterpret_cast<float4*>(op) = y;
}

// ---------------- MFMA GEMM: gload_lds + pre-swizzled source + 2-phase dbuf ----------------
// C[i][j] = sum_k A[i][k] * B[j][k]   (B row-major, K contiguous)
// MODE 0: z=blockIdx.z; A=[meanb5[:,z*512:] | xb] (K=1024), B=w1[z]; epilogue bias->ReLU->BN -> hb
// MODE 1: A=hb (K=2560), B=w23 (1024 rows); j<512 -> zbuf f32; j>=512 -> d_out raw
template<int MODE>
__global__ __launch_bounds__(256, 4)
void gemm_kernel(const unsigned short* __restrict__ A,
                 const unsigned short* __restrict__ A2,
                 const unsigned short* __restrict__ B,
                 unsigned short* __restrict__ hOut,
                 float* __restrict__ fOut,
                 float* __restrict__ fOut2,
                 const float* __restrict__ p0,   // MODE0: bl5
                 const float* __restrict__ p1,   // MODE0: rmean
                 const float* __restrict__ p2,   // MODE0: rvar
                 const float* __restrict__ p3,   // MODE0: gamma
                 const float* __restrict__ p4,   // MODE0: beta
                 int M)
{
  constexpr int KTOT = (MODE == 0) ? (2 * INCH) : CATW;
  constexpr int KT = KTOT / 32;              // 32 / 80 (both even)
  constexpr int NBLK = (MODE == 0) ? 4 : 8;  // output cols / 128

  // bijective XCD-chunked swizzle (m204), col-fastest within an XCD chunk
  const int nwg = gridDim.x;
  const int o = blockIdx.x;
  const int q = nwg >> 3, r = nwg & 7;
  const int xcd = o & 7;
  const int wg = (xcd < r ? xcd * (q + 1) : r * (q + 1) + (xcd - r) * q) + (o >> 3);
  const int rowBase = (wg / NBLK) * 128;
  const int nBase = (wg % NBLK) * 128;
  const int z = (MODE == 0) ? blockIdx.z : 0;
  const unsigned short* Bp = (MODE == 0) ? (B + (size_t)z * 512 * 1024) : B;

  __shared__ unsigned short A_lds[2][4096];   // dbuf x [128 rows][32 k], 16KB each side
  __shared__ unsigned short B_lds[2][4096];

  const int tid = threadIdx.x;
  const int lane = tid & 63;
  const int wv = tid >> 6;                 // 0..3
  const int wr = wv >> 1, wc = wv & 1;
  const int lr = lane & 15, kg = lane >> 4;

  // staging: wave wv stages chunks {2wv,2wv+1} (16 rows x 32k each). LDS dest is linear
  // (gload_lds constraint); SOURCE k-chunk is XOR-pre-swizzled so slot s holds global
  // chunk s ^ ((row>>2)&3)  ->  conflict-free ds_read_b128 (2 lanes/bank).
  const int srow0 = (wv * 2) * 16 + (lane >> 2);
  const int srow1 = (wv * 2 + 1) * 16 + (lane >> 2);
  const int skoff = (((lane & 3) ^ ((lane >> 4) & 3)) * 8);   // elements
  int gar0 = rowBase + srow0; if (gar0 >= M) gar0 = M - 1;
  int gar1 = rowBase + srow1; if (gar1 >= M) gar1 = M - 1;
  const size_t gbr0 = (size_t)(nBase + srow0) * KTOT;
  const size_t gbr1 = (size_t)(nBase + srow1) * KTOT;

  int aslot[4], bslot[4];
#pragma unroll
  for (int m = 0; m < 4; ++m) {
    const int ar = wr * 64 + m * 16 + lr;
    aslot[m] = ar * 32 + ((kg ^ ((lr >> 2) & 3)) * 8);
    const int br = wc * 64 + m * 16 + lr;
    bslot[m] = br * 32 + ((kg ^ ((lr >> 2) & 3)) * 8);
  }

  f32x4 acc[4][4] = {};

  auto stage = [&](int buf, int kt) {
    const int kk0 = kt * 32;
    const unsigned short *a0p, *a1p;
    if (MODE == 0) {
      if (kk0 < INCH) {
        a0p = A + (size_t)gar0 * CATW + z * 512 + kk0 + skoff;
        a1p = A + (size_t)gar1 * CATW + z * 512 + kk0 + skoff;
      } else {
        a0p = A2 + (size_t)gar0 * INCH + (kk0 - INCH) + skoff;
        a1p = A2 + (size_t)gar1 * INCH + (kk0 - INCH) + skoff;
      }
    } else {
      a0p = A + (size_t)gar0 * KTOT + kk0 + skoff;
      a1p = A + (size_t)gar1 * KTOT + kk0 + skoff;
    }
    const unsigned short* b0p = Bp + gbr0 + kk0 + skoff;
    const unsigned short* b1p = Bp + gbr1 + kk0 + skoff;
    __builtin_amdgcn_global_load_lds((const void*)a0p, (void*)&A_lds[buf][(wv * 2) * 512], 16, 0, 0);
    __builtin_amdgcn_global_load_lds((const void*)a1p, (void*)&A_lds[buf][(wv * 2 + 1) * 512], 16, 0, 0);
    __builtin_amdgcn_global_load_lds((const void*)b0p, (void*)&B_lds[buf][(wv * 2) * 512], 16, 0, 0);
    __builtin_amdgcn_global_load_lds((const void*)b1p, (void*)&B_lds[buf][(wv * 2 + 1) * 512], 16, 0, 0);
  };

  auto compute = [&](int buf) {
    bf16x8 af[4], bfv[4];
#pragma unroll
    for (int m = 0; m < 4; ++m) af[m] = *reinterpret_cast<const bf16x8*>(&A_lds[buf][aslot[m]]);
#pragma unroll
    for (int n = 0; n < 4; ++n) bfv[n] = *reinterpret_cast<const bf16x8*>(&B_lds[buf][bslot[n]]);
#pragma unroll
    for (int m = 0; m < 4; ++m)
#pragma unroll
      for (int n = 0; n < 4; ++n)
        acc[m][n] = __builtin_amdgcn_mfma_f32_16x16x32_bf16(af[m], bfv[n], acc[m][n], 0, 0, 0);
  };

  // 2-phase pipeline: stage t+1 while computing t; one barrier (vmcnt drain) per iter.
  stage(0, 0);
  __syncthreads();
  for (int kt = 0; kt + 2 <= KT; kt += 2) {
    stage(1, kt + 1);
    compute(0);
    __syncthreads();
    if (kt + 2 < KT) stage(0, kt + 2);
    compute(1);
    __syncthreads();
  }

#pragma unroll
  for (int n = 0; n < 4; ++n) {
    const int j = nBase + wc * 64 + n * 16 + lr;
    if (MODE == 0) {
      const int ch = z * 512 + j;
      const float bias = p0[ch];
      const float scale = rsqrtf(p2[ch] + BN_EPS) * p3[ch];
      const float rm = p1[ch], be = p4[ch];
#pragma unroll
      for (int m = 0; m < 4; ++m) {
        const int ib = rowBase + wr * 64 + m * 16 + kg * 4;
#pragma unroll
        for (int rr = 0; rr < 4; ++rr) {
          const int i = ib + rr;
          if (i < M) {
            float v = acc[m][n][rr] + bias;   // SAGE output
            v = fmaxf(v, 0.0f);               // ReLU FIRST (reference order)
            v = (v - rm) * scale + be;        // BN SECOND
            hOut[(size_t)i * CATW + ch] = f2bf(v);
          }
        }
      }
    } else {
#pragma unroll
      for (int m = 0; m < 4; ++m) {
        const int ib = rowBase + wr * 64 + m * 16 + kg * 4;
#pragma unroll
        for (int rr = 0; rr < 4; ++rr) {
          const int i = ib + rr;
          if (i < M) {
            const float v = acc[m][n][rr];
            if (j < 512) {
              fOut[(size_t)i * 512 + j] = v;                 // zbuf
            } else {
              const int jj = j - 512;
              size_t o2 = (jj < OUTW) ? ((size_t)i * OUTW + jj)
                                      : ((size_t)M * OUTW + (size_t)i * OUTW + (jj - OUTW));
              fOut2[o2] = v;                                 // y3 (raw, bias added later)
            }
          }
        }
      }
    }
  }
}

// ---------------- launch ----------------

extern "C" void kernel_launch(void* const* d_in, const int* in_sizes, int n_in,
                              void* d_out, int out_size, void* d_ws, size_t ws_size,
                              hipStream_t stream) {
  const float* x     = (const float*)d_in[0];
  const int*   ei    = (const int*)d_in[1];
  const int*   ea    = (const int*)d_in[2];
  const float* Wl5   = (const float*)d_in[3];
  const float* Wr5   = (const float*)d_in[4];
  const float* bl5   = (const float*)d_in[5];
  const float* Wmu_l = (const float*)d_in[6];
  const float* Wmu_r = (const float*)d_in[7];
  const float* bmu   = (const float*)d_in[8];
  const float* Wlv_l = (const float*)d_in[9];
  const float* Wlv_r = (const float*)d_in[10];
  const float* blv   = (const float*)d_in[11];
  const float* gamma = (const float*)d_in[12];
  const float* beta  = (const float*)d_in[13];
  const float* rmean = (const float*)d_in[14];
  const float* rvar  = (const float*)d_in[15];
  (void)n_in; (void)out_size;

  const int N = in_sizes[0] / INCH;   // 20000
  const int E = in_sizes[2];          // 100000
  const int NKEY = N * 5;

  // ---- workspace layout (~243 MB) ----
  char* ws = (char*)d_ws;
  size_t off = 0;
  auto take = [&](size_t bytes) { char* p = ws + off; off += (bytes + 255) & ~(size_t)255; return p; };
  unsigned short* hb = (unsigned short*)take((size_t)N * CATW * 2);      // 102.4 MB
  char* U = take((size_t)N * CATW * 2);                                  // 102.4 MB: meanb5, later zbuf+mean2
  unsigned short* xb = (unsigned short*)take((size_t)N * 512 * 2);       // 20.5 MB
  unsigned short* w1  = (unsigned short*)take((size_t)5 * 512 * 1024 * 2);
  unsigned short* w23 = (unsigned short*)take((size_t)1024 * CATW * 2);  // [w2;w3]
  int* cntk  = (int*)take((size_t)NKEY * 4);
  int* offs  = (int*)take((size_t)(NKEY + 1) * 4);
  int* fillc = (int*)take((size_t)NKEY * 4);
  int* perm  = (int*)take((size_t)E * 4);
  int* bsum  = (int*)take(256 * 4);
  if (off > ws_size) return;  // diagnostic guard -> clean absmax-488 failure

  unsigned short* meanb5 = (unsigned short*)U;         // [N,5,512] bf16 (layer-1 life)
  float* zbuf  = (float*)U;                            // [N,512] f32 (layer-2 life)
  float* mean2 = (float*)(U + (size_t)N * 512 * 4);    // [N,512] f32

  // conversions / packing
  cvt_bf16_kernel<<<dim3((N * INCH / 4 + 255) / 256), 256, 0, stream>>>(x, xb, N * INCH / 4);
  pack_w1_kernel<<<dim3((5 * 512 * 1024 / 4 + 255) / 256), 256, 0, stream>>>(Wl5, Wr5, w1);
  pack_lr_kernel<<<dim3((512 * CATW / 4 + 255) / 256), 256, 0, stream>>>(Wmu_l, Wlv_l, w23);
  pack_lr_kernel<<<dim3((512 * CATW / 4 + 255) / 256), 256, 0, stream>>>(Wmu_r, Wlv_r,
                                                                         w23 + (size_t)512 * CATW);

  // CSR build: key = dst*5 + rel
  hipMemsetAsync(cntk, 0, (size_t)NKEY * 4, stream);
  hipMemsetAsync(fillc, 0, (size_t)NKEY * 4, stream);
  hist_kernel<<<dim3((E + 255) / 256), 256, 0, stream>>>(ei, ea, cntk, E);
  const int nb = (NKEY + TS - 1) / TS;
  scan1_kernel<<<dim3(nb), 256, 0, stream>>>(cntk, offs, bsum, NKEY);
  scan2_kernel<<<dim3(1), 128, 0, stream>>>(bsum, nb);
  scan3_kernel<<<dim3((NKEY / 4 + 255) / 256 + 1), 256, 0, stream>>>(offs, bsum, NKEY, E);
  fill_kernel<<<dim3((E + 255) / 256), 256, 0, stream>>>(ei, ea, offs, fillc, perm, E);

  // layer 1: all 5 relation means, then ONE batched GEMM dispatch (z = relation)
  gather1_kernel<<<dim3(N, 5), 128, 0, stream>>>(xb, offs, perm, meanb5);
  const int mblk = (N + 127) / 128;
  gemm_kernel<0><<<dim3(mblk * 4, 1, 5), 256, 0, stream>>>(
      meanb5, xb, w1, hb, nullptr, nullptr,
      bl5, rmean, rvar, gamma, beta, N);

  // layer 2: one pass over hb computes z (->zbuf) and y3 (->d_out)
  gemm_kernel<1><<<dim3(mblk * 8, 1, 1), 256, 0, stream>>>(
      hb, nullptr, w23, nullptr, zbuf, (float*)d_out,
      nullptr, nullptr, nullptr, nullptr, nullptr, N);

  gather2_kernel<<<dim3(N), 128, 0, stream>>>(zbuf, offs, perm, mean2);

  add_kernel<<<dim3((N * 512 / 4 + 255) / 256), 256, 0, stream>>>(
      (float*)d_out, mean2, bmu, blv, N, N * 512 / 4);
}